// Round 10
// baseline (199.386 us; speedup 1.0000x reference)
//
#include <hip/hip_runtime.h>
#include <hip/hip_bf16.h>
#include <stdint.h>

// Problem constants (fixed by the reference)
#define TSEQ 4096
#define CEMB 1024
#define DH   64
#define NB   4
#define NCHUNK 4      // KV-split factor per q-tile (flash-decoding style)

typedef __attribute__((ext_vector_type(8))) short bf16x8;  // 8 bf16 (4 VGPRs) MFMA frag
typedef __attribute__((ext_vector_type(4))) float f32x4;   // MFMA accum frag
typedef __attribute__((ext_vector_type(4))) float f4;
typedef unsigned short u16;

// fp32 -> bf16 (compiler-generated convert; m240: don't hand-write cvt)
__device__ __forceinline__ u16 f2bf(float f) {
  __hip_bfloat16 h = __float2bfloat16(f);
  return *(u16*)&h;
}

// XOR-swizzled byte offset inside an LDS tile with 128-byte rows (64 bf16/row).
__device__ __forceinline__ int swz(int row, int colbyte) {
  return row * 128 + (colbyte ^ ((row & 7) << 4));
}

// ---------------------------------------------------------------------------
// prep: W[1024][64] fp32 (q,k,v) -> wt[3*64][1024] bf16 (transposed).
// ---------------------------------------------------------------------------
__global__ void prep_w(const float* __restrict__ Wq, const float* __restrict__ Wk,
                       const float* __restrict__ Wv, u16* __restrict__ wt) {
  int idx = blockIdx.x * 256 + threadIdx.x;
  if (idx >= 3 * DH * CEMB) return;
  int m = idx >> 16;            // which matrix
  int r = idx & 65535;          // index into W (row-major [k][n])
  int k = r >> 6, n = r & 63;
  const float* W = (m == 0) ? Wq : (m == 1) ? Wk : Wv;
  wt[(size_t)m * 65536 + n * 1024 + k] = f2bf(W[r]);
}

// ---------------------------------------------------------------------------
// Fused QKV projection GEMM, LDS-FREE: C[32 x 192] = X[32 x 1024] @ Wt^T.
// Fragments loaded DIRECTLY from global (wt L2-resident); no LDS, no barriers
// -> compiler can software-pipeline next K-step's loads under current MFMAs.
// __launch_bounds__(256, 2): min 2 waves/EU -> VGPR cap ~256 (round-9 failure:
// default bounds pinned VGPR=48, serializing the 14-load pipeline -> 3% util).
// 4 waves = 2 row-groups x 2 col-groups. RoPE in epilogue; q pre-scaled by
// 0.125; v stored transposed vt[b][d][t].
// ---------------------------------------------------------------------------
__launch_bounds__(256, 2)
__global__ void qkv_gemm(const float* __restrict__ x, const u16* __restrict__ wt,
                         const float* __restrict__ fc, const float* __restrict__ fs,
                         u16* __restrict__ q_ws, u16* __restrict__ k_ws,
                         u16* __restrict__ vt_ws) {
  const int tid  = threadIdx.x;
  const int lane = tid & 63;
  const int w    = tid >> 6;
  const int l15  = lane & 15;
  const int lhi  = lane >> 4;
  const int rg   = w & 1;              // row-group (16 rows)
  const int cg   = w >> 1;             // col-group (96 cols)
  const int m0   = blockIdx.x * 32;

  const float* xr = x + (size_t)(m0 + rg * 16 + l15) * CEMB + lhi * 8;  // A row base
  // hoisted B-row bases (6 rows, 16*CEMB apart)
  const u16* wb0 = wt + (size_t)(cg * 96 + l15) * CEMB + lhi * 8;
  const u16* wb1 = wb0 + (size_t)16 * CEMB;
  const u16* wb2 = wb0 + (size_t)32 * CEMB;
  const u16* wb3 = wb0 + (size_t)48 * CEMB;
  const u16* wb4 = wb0 + (size_t)64 * CEMB;
  const u16* wb5 = wb0 + (size_t)80 * CEMB;

  const f32x4 z4 = {0.f, 0.f, 0.f, 0.f};
  f32x4 acc[6];
#pragma unroll
  for (int j = 0; j < 6; ++j) acc[j] = z4;

#pragma unroll 2
  for (int k0 = 0; k0 < CEMB; k0 += 64) {
#pragma unroll
    for (int kk = 0; kk < 2; ++kk) {
      const int ko = k0 + kk * 32;
      // B fragments: 6 independent 16B loads (L2-hot)
      bf16x8 b0 = *(const bf16x8*)(wb0 + ko);
      bf16x8 b1 = *(const bf16x8*)(wb1 + ko);
      bf16x8 b2 = *(const bf16x8*)(wb2 + ko);
      bf16x8 b3 = *(const bf16x8*)(wb3 + ko);
      bf16x8 b4 = *(const bf16x8*)(wb4 + ko);
      bf16x8 b5 = *(const bf16x8*)(wb5 + ko);
      // A fragment: 8 fp32 -> bf16 in-lane
      f4 a = *(const f4*)(xr + ko);
      f4 b = *(const f4*)(xr + ko + 4);
      bf16x8 af;
      af[0] = (short)f2bf(a[0]); af[1] = (short)f2bf(a[1]);
      af[2] = (short)f2bf(a[2]); af[3] = (short)f2bf(a[3]);
      af[4] = (short)f2bf(b[0]); af[5] = (short)f2bf(b[1]);
      af[6] = (short)f2bf(b[2]); af[7] = (short)f2bf(b[3]);
      acc[0] = __builtin_amdgcn_mfma_f32_16x16x32_bf16(af, b0, acc[0], 0, 0, 0);
      acc[1] = __builtin_amdgcn_mfma_f32_16x16x32_bf16(af, b1, acc[1], 0, 0, 0);
      acc[2] = __builtin_amdgcn_mfma_f32_16x16x32_bf16(af, b2, acc[2], 0, 0, 0);
      acc[3] = __builtin_amdgcn_mfma_f32_16x16x32_bf16(af, b3, acc[3], 0, 0, 0);
      acc[4] = __builtin_amdgcn_mfma_f32_16x16x32_bf16(af, b4, acc[4], 0, 0, 0);
      acc[5] = __builtin_amdgcn_mfma_f32_16x16x32_bf16(af, b5, acc[5], 0, 0, 0);
    }
  }

  // epilogue: D row = (lane>>4)*4 + r, col = lane&15
#pragma unroll
  for (int nc = 0; nc < 6; ++nc) {
    int gcol = cg * 96 + nc * 16 + l15;   // 0..191
    int mat  = gcol >> 6;                 // 0=q 1=k 2=v
    int col  = gcol & 63;                 // head dim
#pragma unroll
    for (int r = 0; r < 4; ++r) {
      float v = acc[nc][r];
      float o = __shfl_xor(v, 1);         // RoPE pair partner (adjacent col)
      int row = m0 + rg * 16 + lhi * 4 + r;
      int b = row >> 12, t = row & 4095;
      if (mat == 2) {
        vt_ws[((size_t)(b * DH + col)) * TSEQ + t] = f2bf(v);
      } else {
        int p = col >> 1;
        float cv = fc[t * 32 + p], sv = fs[t * 32 + p];
        float outv = ((col & 1) == 0) ? (v * cv - o * sv)   // real part
                                      : (o * sv + v * cv);  // imag part
        if (mat == 0) outv *= 0.125f;     // fold attention scale into q (pow2, exact)
        u16* dst = (mat == 0) ? q_ws : k_ws;
        dst[(size_t)row * DH + col] = f2bf(outv);
      }
    }
  }
}

// ---------------------------------------------------------------------------
// Flash attention partials, causal, KV-chunked. QBLK=64 (4 waves x 16 rows),
// KVBLK=64, single-buffered LDS (24 KB -> 6 blocks/CU), issue-early loads.
// COMPLEMENTARY-LENGTH CU PAIRING: grid (256,4); blocks f and f+256 share a
// CU (round-robin), j-odd blocks take qt=63-r -> every CU hosts ~34 tile-steps.
// ---------------------------------------------------------------------------
#define ATT_LOADKV(KV0) \
    _Pragma("unroll") for (int it = 0; it < 2; ++it) { \
      int gg = it * 256 + tid, row_ = gg >> 3, cc_ = gg & 7; \
      kreg[it] = *(const bf16x8*)(kb + (size_t)((KV0) + row_) * DH + cc_ * 8); \
      vreg[it] = *(const bf16x8*)(vb + (size_t)row_ * TSEQ + (KV0) + cc_ * 8); }
#define ATT_WRITEKV \
    _Pragma("unroll") for (int it = 0; it < 2; ++it) { \
      int gg = it * 256 + tid, row_ = gg >> 3, cc_ = gg & 7; \
      *(bf16x8*)((char*)kt + swz(row_, cc_ << 4)) = kreg[it]; \
      *(bf16x8*)((char*)vts + swz(row_, cc_ << 4)) = vreg[it]; }

__launch_bounds__(256)
__global__ void attn_partial(const u16* __restrict__ q_ws, const u16* __restrict__ k_ws,
                             const u16* __restrict__ vt_ws, float* __restrict__ po,
                             float* __restrict__ pml) {
  const int g  = blockIdx.x;                    // 0..255
  const int j  = blockIdx.y;                    // 0..3
  const int b  = g >> 6;
  const int r0 = g & 63;
  const int qt = (j & 1) ? (63 - r0) : r0;      // complementary pairing
  const int c  = j;

  const int ntiles = qt + 1;                    // causal KV-tiles for this qtile
  const int cnt    = (ntiles + NCHUNK - 1) / NCHUNK;
  const int t0     = c * cnt;
  if (t0 >= ntiles) return;                     // dead chunk (uniform exit, pre-barrier)
  const int t1     = min(t0 + cnt, ntiles);

  __shared__ __align__(16) u16 kt[64 * 64];      // K tile, swizzled (8 KB)
  __shared__ __align__(16) u16 vts[64 * 64];     // V^T tile, swizzled (8 KB)
  __shared__ __align__(16) u16 pt2[4 * 16 * 64]; // per-wave P, swizzled (8 KB)

  const int tid  = threadIdx.x;
  const int lane = tid & 63;
  const int w    = tid >> 6;
  const int l15  = lane & 15;
  const int lhi  = lane >> 4;
  const int q0   = qt * 64;

  const u16* qb = q_ws + (size_t)b * TSEQ * DH;
  const u16* kb = k_ws + (size_t)b * TSEQ * DH;
  const u16* vb = vt_ws + (size_t)b * DH * TSEQ;
  char* ptw = (char*)pt2 + w * 2048;            // this wave's P region

  // Q fragments (A operand, rows = this wave's 16 q-rows); q pre-scaled by 0.125
  bf16x8 aq[2];
  {
    int qrow = q0 + w * 16 + l15;
#pragma unroll
    for (int kk = 0; kk < 2; ++kk)
      aq[kk] = *(const bf16x8*)(qb + (size_t)qrow * DH + kk * 32 + lhi * 8);
  }

  const f32x4 z4 = {0.f, 0.f, 0.f, 0.f};
  f32x4 oacc[4] = {z4, z4, z4, z4};
  float m_r[4], l_p[4];                         // l_p = per-LANE partial sum
#pragma unroll
  for (int r = 0; r < 4; ++r) { m_r[r] = -1e30f; l_p[r] = 0.f; }

  const int myqbase = q0 + w * 16 + lhi * 4;    // + r = this lane's q rows

  bf16x8 kreg[2], vreg[2];

  for (int kv = t0; kv < t1; ++kv) {
    const int kv0 = kv * 64;
    ATT_LOADKV(kv0)                   // issue loads; latency hides under barrier
    __syncthreads();                  // all waves done reading previous tile
    ATT_WRITEKV
    __syncthreads();

    // ---- S = Q K^T (16 x 64 per wave), scale pre-folded into q ----
    f32x4 sacc[4] = {z4, z4, z4, z4};
    __builtin_amdgcn_s_setprio(1);
#pragma unroll
    for (int kk = 0; kk < 2; ++kk) {
#pragma unroll
      for (int cb = 0; cb < 4; ++cb) {
        bf16x8 bk = *(const bf16x8*)((char*)kt + swz(cb * 16 + l15, (kk * 32 + lhi * 8) * 2));
        sacc[cb] = __builtin_amdgcn_mfma_f32_16x16x32_bf16(aq[kk], bk, sacc[cb], 0, 0, 0);
      }
    }
    __builtin_amdgcn_s_setprio(0);

    // ---- causal mask: DIAGONAL TILE ONLY (interior tiles fully unmasked) ----
    if (kv0 == q0) {
#pragma unroll
      for (int cb = 0; cb < 4; ++cb)
#pragma unroll
        for (int r = 0; r < 4; ++r) {
          int ki = kv0 + cb * 16 + l15;
          int qi = myqbase + r;
          if (ki > qi) sacc[cb][r] = -1e30f;
        }
    }
    // ---- row max (uniform across each 16-lane row group after reduce) ----
    float mx[4];
#pragma unroll
    for (int r = 0; r < 4; ++r)
      mx[r] = fmaxf(fmaxf(sacc[0][r], sacc[1][r]), fmaxf(sacc[2][r], sacc[3][r]));
#pragma unroll
    for (int s = 1; s <= 8; s <<= 1)
#pragma unroll
      for (int r = 0; r < 4; ++r) mx[r] = fmaxf(mx[r], __shfl_xor(mx[r], s));
    // ---- defer-max: skip rescale unless max grew by > 8 ----
    bool skip = true;
#pragma unroll
    for (int r = 0; r < 4; ++r) skip = skip && (mx[r] <= m_r[r] + 8.f);
    if (!__all(skip)) {
#pragma unroll
      for (int r = 0; r < 4; ++r) {
        float mn = fmaxf(m_r[r], mx[r]);
        float fac = __expf(m_r[r] - mn);
        m_r[r] = mn;
        l_p[r] *= fac;
#pragma unroll
        for (int nc = 0; nc < 4; ++nc) oacc[nc][r] *= fac;
      }
    }
    // ---- P = exp(S - m), per-lane l accumulation, P -> LDS (bf16) ----
#pragma unroll
    for (int cb = 0; cb < 4; ++cb)
#pragma unroll
      for (int r = 0; r < 4; ++r) {
        float p = __expf(sacc[cb][r] - m_r[r]);
        l_p[r] += p;
        *(u16*)(ptw + swz(lhi * 4 + r, (cb * 16 + l15) * 2)) = f2bf(p);
      }
    bf16x8 ap[2];
#pragma unroll
    for (int kk = 0; kk < 2; ++kk)
      ap[kk] = *(const bf16x8*)(ptw + swz(l15, (kk * 32 + lhi * 8) * 2));
    // ---- O += P V ----
    __builtin_amdgcn_s_setprio(1);
#pragma unroll
    for (int kk = 0; kk < 2; ++kk)
#pragma unroll
      for (int nc = 0; nc < 4; ++nc) {
        bf16x8 bv = *(const bf16x8*)((char*)vts + swz(nc * 16 + l15, (kk * 32 + lhi * 8) * 2));
        oacc[nc] = __builtin_amdgcn_mfma_f32_16x16x32_bf16(ap[kk], bv, oacc[nc], 0, 0, 0);
      }
    __builtin_amdgcn_s_setprio(0);
  }

  // ---- deferred cross-lane l reduction (once per kernel, not per step) ----
#pragma unroll
  for (int s = 1; s <= 8; s <<= 1)
#pragma unroll
    for (int r = 0; r < 4; ++r) l_p[r] += __shfl_xor(l_p[r], s);

  // write partial: O (no div), m, l
  const int slot = ((b * 64 + qt) * NCHUNK + c);
  float* o_out = po + (size_t)slot * (64 * 64);
#pragma unroll
  for (int nc = 0; nc < 4; ++nc)
#pragma unroll
    for (int r = 0; r < 4; ++r) {
      int rloc = w * 16 + lhi * 4 + r;
      o_out[rloc * 64 + nc * 16 + l15] = oacc[nc][r];
    }
#pragma unroll
  for (int r = 0; r < 4; ++r) {
    if (l15 == 0) {                        // one writer per row
      int rloc = w * 16 + lhi * 4 + r;
      pml[(size_t)slot * 128 + rloc]      = m_r[r];
      pml[(size_t)slot * 128 + 64 + rloc] = l_p[r];
    }
  }
}

// ---------------------------------------------------------------------------
// Combine partials: out[b][t][d] = sum_c e^{m_c-M} O_c[d] / sum_c e^{m_c-M} l_c
// ---------------------------------------------------------------------------
__launch_bounds__(256)
__global__ void attn_combine(const float* __restrict__ po, const float* __restrict__ pml,
                             float* __restrict__ out) {
  int idx = blockIdx.x * 256 + threadIdx.x;    // idx over B*T*DH = 1M
  int d   = idx & 63;
  int t   = (idx >> 6) & 4095;
  int b   = idx >> 18;
  int qt  = t >> 6;
  int rloc = t & 63;
  int ntiles = qt + 1;
  int cnt = (ntiles + NCHUNK - 1) / NCHUNK;

  float m_c[NCHUNK], l_c[NCHUNK], o_c[NCHUNK];
  float M = -1e30f;
#pragma unroll
  for (int c = 0; c < NCHUNK; ++c) {
    bool valid = (c * cnt < ntiles);
    int slot = ((b * 64 + qt) * NCHUNK + c);
    m_c[c] = valid ? pml[(size_t)slot * 128 + rloc]      : -1e30f;
    l_c[c] = valid ? pml[(size_t)slot * 128 + 64 + rloc] : 0.f;
    o_c[c] = valid ? po[(size_t)slot * (64 * 64) + rloc * 64 + d] : 0.f;
    M = fmaxf(M, m_c[c]);
  }
  float den = 0.f, num = 0.f;
#pragma unroll
  for (int c = 0; c < NCHUNK; ++c) {
    float e = __expf(m_c[c] - M);
    den += e * l_c[c];
    num += e * o_c[c];
  }
  out[idx] = num / den;
}

// ---------------------------------------------------------------------------
extern "C" void kernel_launch(void* const* d_in, const int* in_sizes, int n_in,
                              void* d_out, int out_size, void* d_ws, size_t ws_size,
                              hipStream_t stream) {
  const float* x  = (const float*)d_in[0];
  const float* Wq = (const float*)d_in[1];
  const float* Wk = (const float*)d_in[2];
  const float* Wv = (const float*)d_in[3];
  const float* fc = (const float*)d_in[4];
  const float* fs = (const float*)d_in[5];
  float* out = (float*)d_out;

  // workspace layout (~23 MB):
  char* ws = (char*)d_ws;
  u16*   wt    = (u16*)(ws);                                   // 384 KB (pad 512K)
  u16*   q_ws  = (u16*)(ws + (1u << 19));                      // 2 MB
  u16*   k_ws  = (u16*)(ws + (1u << 19) + (1u << 21));         // 2 MB
  u16*   vt_ws = (u16*)(ws + (1u << 19) + (2u << 21));         // 2 MB
  float* po    = (float*)(ws + (1u << 19) + (3u << 21));       // 1024*4096*4 = 16 MB
  float* pml   = (float*)(ws + (1u << 19) + (3u << 21) + (1u << 24)); // 512 KB

  prep_w<<<(3 * DH * CEMB + 255) / 256, 256, 0, stream>>>(Wq, Wk, Wv, wt);
  qkv_gemm<<<dim3(512), 256, 0, stream>>>(x, wt, fc, fs, q_ws, k_ws, vt_ws);
  attn_partial<<<dim3(256, NCHUNK), 256, 0, stream>>>(q_ws, k_ws, vt_ws, po, pml);
  attn_combine<<<dim3((NB * TSEQ * DH) / 256), 256, 0, stream>>>(po, pml, out);
}

// Round 13
// 172.006 us; speedup vs baseline: 1.1592x; 1.1592x over previous
//
#include <hip/hip_runtime.h>
#include <hip/hip_bf16.h>
#include <stdint.h>

// Problem constants (fixed by the reference)
#define TSEQ 4096
#define CEMB 1024
#define DH   64
#define NB   4
#define NCHUNK 4      // KV-split factor per q-tile (flash-decoding style)

typedef __attribute__((ext_vector_type(8))) short bf16x8;  // 8 bf16 (4 VGPRs) MFMA frag
typedef __attribute__((ext_vector_type(4))) float f32x4;   // MFMA accum frag
typedef __attribute__((ext_vector_type(4))) float f4;
typedef unsigned short u16;

// fp32 -> bf16 (compiler-generated convert; m240: don't hand-write cvt)
__device__ __forceinline__ u16 f2bf(float f) {
  __hip_bfloat16 h = __float2bfloat16(f);
  return *(u16*)&h;
}

// XOR-swizzled byte offset inside an LDS tile with 128-byte rows (64 bf16/row).
__device__ __forceinline__ int swz(int row, int colbyte) {
  return row * 128 + (colbyte ^ ((row & 7) << 4));
}

// ---------------------------------------------------------------------------
// prep: W fp32 (q,k,v) -> wf, FRAGMENT-ORDERED bf16 B-fragment stream:
//   wf[((ncg*32 + ku)*64 + lane)*8 + j] = W[k][n]
//   where col_g = ncg*16 + (lane&15)  (global col: mat = col_g>>6, n = col_g&63)
//         k     = ku*32 + (lane>>4)*8 + j
// A wave's B-frag load for (col-block ncg, K-unit ku) is then ONE contiguous
// coalesced 1KB read: base + ((ncg*32+ku)<<9) + lane*8. (r10 failure (b): the
// row-major layout put consecutive lanes 2KB apart -> 16 segments per load.)
// ---------------------------------------------------------------------------
__global__ void prep_w(const float* __restrict__ Wq, const float* __restrict__ Wk,
                       const float* __restrict__ Wv, u16* __restrict__ wf) {
  int idx = blockIdx.x * 256 + threadIdx.x;
  if (idx >= 3 * DH * CEMB) return;
  int j    = idx & 7;
  int lane = (idx >> 3) & 63;
  int ku   = (idx >> 9) & 31;
  int ncg  = idx >> 14;                 // 0..11
  int col_g = ncg * 16 + (lane & 15);   // 0..191
  int k     = ku * 32 + (lane >> 4) * 8 + j;
  int mat = col_g >> 6, n = col_g & 63;
  const float* W = (mat == 0) ? Wq : (mat == 1) ? Wk : Wv;
  wf[idx] = f2bf(W[k * DH + n]);
}

// ---------------------------------------------------------------------------
// Fused QKV projection GEMM, LDS-free + MANUALLY SOFTWARE-PIPELINED:
// C[32 x 192] = X[32 x 1024] @ W. 4 waves = 2 row-groups x 2 col-groups
// (wave: 16 rows x 96 cols). B-frags stream from the fragment-ordered wf
// (coalesced, L2-resident); A rows read per-lane fp32 + in-lane cvt.
// Two named prefetch buffers (Ba/Bb) loaded 2 K-units ahead -- the dataflow
// forces loads in flight under MFMAs (r10 failure (a): compiler won't
// pipeline on its own; VGPR sank to 40 and every unit serialized).
// RoPE in epilogue; q pre-scaled by 0.125; v stored transposed vt[b][d][t].
// ---------------------------------------------------------------------------
#define LOADB(DST, U) \
    _Pragma("unroll") for (int nc = 0; nc < 6; ++nc) \
      DST[nc] = *(const bf16x8*)(wfb + (((size_t)nc * 32 + (size_t)(U)) << 9));
#define LOADA(FA, FB, U) { const float* s_ = xr + (U) * 32; \
    FA = *(const f4*)s_; FB = *(const f4*)(s_ + 4); }
#define CVT_MFMA(FA, FB, B) { \
    bf16x8 af_; \
    af_[0] = (short)f2bf(FA[0]); af_[1] = (short)f2bf(FA[1]); \
    af_[2] = (short)f2bf(FA[2]); af_[3] = (short)f2bf(FA[3]); \
    af_[4] = (short)f2bf(FB[0]); af_[5] = (short)f2bf(FB[1]); \
    af_[6] = (short)f2bf(FB[2]); af_[7] = (short)f2bf(FB[3]); \
    _Pragma("unroll") for (int nc = 0; nc < 6; ++nc) \
      acc[nc] = __builtin_amdgcn_mfma_f32_16x16x32_bf16(af_, B[nc], acc[nc], 0, 0, 0); }

__launch_bounds__(256, 2)
__global__ void qkv_gemm(const float* __restrict__ x, const u16* __restrict__ wf,
                         const float* __restrict__ fc, const float* __restrict__ fs,
                         u16* __restrict__ q_ws, u16* __restrict__ k_ws,
                         u16* __restrict__ vt_ws) {
  const int tid  = threadIdx.x;
  const int lane = tid & 63;
  const int w    = tid >> 6;
  const int l15  = lane & 15;
  const int lhi  = lane >> 4;
  const int rg   = w & 1;              // row-group (16 rows)
  const int cg   = w >> 1;             // col-group (96 cols = ncg 6*cg .. 6*cg+5)
  const int m0   = blockIdx.x * 32;

  const float* xr  = x + (size_t)(m0 + rg * 16 + l15) * CEMB + lhi * 8;
  const u16*   wfb = wf + (((size_t)(cg * 6) * 32) << 9) + lane * 8;

  const f32x4 z4 = {0.f, 0.f, 0.f, 0.f};
  f32x4 acc[6];
#pragma unroll
  for (int j = 0; j < 6; ++j) acc[j] = z4;

  bf16x8 Ba[6], Bb[6];
  f4 a0, a1, b0, b1;

  // prologue: prefetch K-units 0 and 1
  LOADB(Ba, 0) LOADA(a0, a1, 0)
  LOADB(Bb, 1) LOADA(b0, b1, 1)

  for (int u = 0; u < 32; u += 2) {
    CVT_MFMA(a0, a1, Ba)
    if (u + 2 < 32) { LOADB(Ba, u + 2) LOADA(a0, a1, u + 2) }
    CVT_MFMA(b0, b1, Bb)
    if (u + 3 < 32) { LOADB(Bb, u + 3) LOADA(b0, b1, u + 3) }
  }

  // epilogue: D row = (lane>>4)*4 + r, col = lane&15
#pragma unroll
  for (int nc = 0; nc < 6; ++nc) {
    int gcol = cg * 96 + nc * 16 + l15;   // 0..191
    int mat  = gcol >> 6;                 // 0=q 1=k 2=v
    int col  = gcol & 63;                 // head dim
#pragma unroll
    for (int r = 0; r < 4; ++r) {
      float v = acc[nc][r];
      float o = __shfl_xor(v, 1);         // RoPE pair partner (adjacent col)
      int row = m0 + rg * 16 + lhi * 4 + r;
      int b = row >> 12, t = row & 4095;
      if (mat == 2) {
        vt_ws[((size_t)(b * DH + col)) * TSEQ + t] = f2bf(v);
      } else {
        int p = col >> 1;
        float cv = fc[t * 32 + p], sv = fs[t * 32 + p];
        float outv = ((col & 1) == 0) ? (v * cv - o * sv)   // real part
                                      : (o * sv + v * cv);  // imag part
        if (mat == 0) outv *= 0.125f;     // fold attention scale into q (pow2, exact)
        u16* dst = (mat == 0) ? q_ws : k_ws;
        dst[(size_t)row * DH + col] = f2bf(outv);
      }
    }
  }
}

// ---------------------------------------------------------------------------
// Flash attention partials, causal, KV-chunked. QBLK=64 (4 waves x 16 rows),
// KVBLK=64, single-buffered LDS (24 KB -> 6 blocks/CU), issue-early loads.
// COMPLEMENTARY-LENGTH CU PAIRING: grid (256,4); blocks f and f+256 share a
// CU (round-robin), j-odd blocks take qt=63-r -> every CU hosts ~34 tile-steps.
// ---------------------------------------------------------------------------
#define ATT_LOADKV(KV0) \
    _Pragma("unroll") for (int it = 0; it < 2; ++it) { \
      int gg = it * 256 + tid, row_ = gg >> 3, cc_ = gg & 7; \
      kreg[it] = *(const bf16x8*)(kb + (size_t)((KV0) + row_) * DH + cc_ * 8); \
      vreg[it] = *(const bf16x8*)(vb + (size_t)row_ * TSEQ + (KV0) + cc_ * 8); }
#define ATT_WRITEKV \
    _Pragma("unroll") for (int it = 0; it < 2; ++it) { \
      int gg = it * 256 + tid, row_ = gg >> 3, cc_ = gg & 7; \
      *(bf16x8*)((char*)kt + swz(row_, cc_ << 4)) = kreg[it]; \
      *(bf16x8*)((char*)vts + swz(row_, cc_ << 4)) = vreg[it]; }

__launch_bounds__(256)
__global__ void attn_partial(const u16* __restrict__ q_ws, const u16* __restrict__ k_ws,
                             const u16* __restrict__ vt_ws, float* __restrict__ po,
                             float* __restrict__ pml) {
  const int g  = blockIdx.x;                    // 0..255
  const int j  = blockIdx.y;                    // 0..3
  const int b  = g >> 6;
  const int r0 = g & 63;
  const int qt = (j & 1) ? (63 - r0) : r0;      // complementary pairing
  const int c  = j;

  const int ntiles = qt + 1;                    // causal KV-tiles for this qtile
  const int cnt    = (ntiles + NCHUNK - 1) / NCHUNK;
  const int t0     = c * cnt;
  if (t0 >= ntiles) return;                     // dead chunk (uniform exit, pre-barrier)
  const int t1     = min(t0 + cnt, ntiles);

  __shared__ __align__(16) u16 kt[64 * 64];      // K tile, swizzled (8 KB)
  __shared__ __align__(16) u16 vts[64 * 64];     // V^T tile, swizzled (8 KB)
  __shared__ __align__(16) u16 pt2[4 * 16 * 64]; // per-wave P, swizzled (8 KB)

  const int tid  = threadIdx.x;
  const int lane = tid & 63;
  const int w    = tid >> 6;
  const int l15  = lane & 15;
  const int lhi  = lane >> 4;
  const int q0   = qt * 64;

  const u16* qb = q_ws + (size_t)b * TSEQ * DH;
  const u16* kb = k_ws + (size_t)b * TSEQ * DH;
  const u16* vb = vt_ws + (size_t)b * DH * TSEQ;
  char* ptw = (char*)pt2 + w * 2048;            // this wave's P region

  // Q fragments (A operand, rows = this wave's 16 q-rows); q pre-scaled by 0.125
  bf16x8 aq[2];
  {
    int qrow = q0 + w * 16 + l15;
#pragma unroll
    for (int kk = 0; kk < 2; ++kk)
      aq[kk] = *(const bf16x8*)(qb + (size_t)qrow * DH + kk * 32 + lhi * 8);
  }

  const f32x4 z4 = {0.f, 0.f, 0.f, 0.f};
  f32x4 oacc[4] = {z4, z4, z4, z4};
  float m_r[4], l_p[4];                         // l_p = per-LANE partial sum
#pragma unroll
  for (int r = 0; r < 4; ++r) { m_r[r] = -1e30f; l_p[r] = 0.f; }

  const int myqbase = q0 + w * 16 + lhi * 4;    // + r = this lane's q rows

  bf16x8 kreg[2], vreg[2];

  for (int kv = t0; kv < t1; ++kv) {
    const int kv0 = kv * 64;
    ATT_LOADKV(kv0)                   // issue loads; latency hides under barrier
    __syncthreads();                  // all waves done reading previous tile
    ATT_WRITEKV
    __syncthreads();

    // ---- S = Q K^T (16 x 64 per wave), scale pre-folded into q ----
    f32x4 sacc[4] = {z4, z4, z4, z4};
    __builtin_amdgcn_s_setprio(1);
#pragma unroll
    for (int kk = 0; kk < 2; ++kk) {
#pragma unroll
      for (int cb = 0; cb < 4; ++cb) {
        bf16x8 bk = *(const bf16x8*)((char*)kt + swz(cb * 16 + l15, (kk * 32 + lhi * 8) * 2));
        sacc[cb] = __builtin_amdgcn_mfma_f32_16x16x32_bf16(aq[kk], bk, sacc[cb], 0, 0, 0);
      }
    }
    __builtin_amdgcn_s_setprio(0);

    // ---- causal mask: DIAGONAL TILE ONLY (interior tiles fully unmasked) ----
    if (kv0 == q0) {
#pragma unroll
      for (int cb = 0; cb < 4; ++cb)
#pragma unroll
        for (int r = 0; r < 4; ++r) {
          int ki = kv0 + cb * 16 + l15;
          int qi = myqbase + r;
          if (ki > qi) sacc[cb][r] = -1e30f;
        }
    }
    // ---- row max (uniform across each 16-lane row group after reduce) ----
    float mx[4];
#pragma unroll
    for (int r = 0; r < 4; ++r)
      mx[r] = fmaxf(fmaxf(sacc[0][r], sacc[1][r]), fmaxf(sacc[2][r], sacc[3][r]));
#pragma unroll
    for (int s = 1; s <= 8; s <<= 1)
#pragma unroll
      for (int r = 0; r < 4; ++r) mx[r] = fmaxf(mx[r], __shfl_xor(mx[r], s));
    // ---- defer-max: skip rescale unless max grew by > 8 ----
    bool skip = true;
#pragma unroll
    for (int r = 0; r < 4; ++r) skip = skip && (mx[r] <= m_r[r] + 8.f);
    if (!__all(skip)) {
#pragma unroll
      for (int r = 0; r < 4; ++r) {
        float mn = fmaxf(m_r[r], mx[r]);
        float fac = __expf(m_r[r] - mn);
        m_r[r] = mn;
        l_p[r] *= fac;
#pragma unroll
        for (int nc = 0; nc < 4; ++nc) oacc[nc][r] *= fac;
      }
    }
    // ---- P = exp(S - m), per-lane l accumulation, P -> LDS (bf16) ----
#pragma unroll
    for (int cb = 0; cb < 4; ++cb)
#pragma unroll
      for (int r = 0; r < 4; ++r) {
        float p = __expf(sacc[cb][r] - m_r[r]);
        l_p[r] += p;
        *(u16*)(ptw + swz(lhi * 4 + r, (cb * 16 + l15) * 2)) = f2bf(p);
      }
    bf16x8 ap[2];
#pragma unroll
    for (int kk = 0; kk < 2; ++kk)
      ap[kk] = *(const bf16x8*)(ptw + swz(l15, (kk * 32 + lhi * 8) * 2));
    // ---- O += P V ----
    __builtin_amdgcn_s_setprio(1);
#pragma unroll
    for (int kk = 0; kk < 2; ++kk)
#pragma unroll
      for (int nc = 0; nc < 4; ++nc) {
        bf16x8 bv = *(const bf16x8*)((char*)vts + swz(nc * 16 + l15, (kk * 32 + lhi * 8) * 2));
        oacc[nc] = __builtin_amdgcn_mfma_f32_16x16x32_bf16(ap[kk], bv, oacc[nc], 0, 0, 0);
      }
    __builtin_amdgcn_s_setprio(0);
  }

  // ---- deferred cross-lane l reduction (once per kernel, not per step) ----
#pragma unroll
  for (int s = 1; s <= 8; s <<= 1)
#pragma unroll
    for (int r = 0; r < 4; ++r) l_p[r] += __shfl_xor(l_p[r], s);

  // write partial: O (no div), m, l
  const int slot = ((b * 64 + qt) * NCHUNK + c);
  float* o_out = po + (size_t)slot * (64 * 64);
#pragma unroll
  for (int nc = 0; nc < 4; ++nc)
#pragma unroll
    for (int r = 0; r < 4; ++r) {
      int rloc = w * 16 + lhi * 4 + r;
      o_out[rloc * 64 + nc * 16 + l15] = oacc[nc][r];
    }
#pragma unroll
  for (int r = 0; r < 4; ++r) {
    if (l15 == 0) {                        // one writer per row
      int rloc = w * 16 + lhi * 4 + r;
      pml[(size_t)slot * 128 + rloc]      = m_r[r];
      pml[(size_t)slot * 128 + 64 + rloc] = l_p[r];
    }
  }
}

// ---------------------------------------------------------------------------
// Combine partials: out[b][t][d] = sum_c e^{m_c-M} O_c[d] / sum_c e^{m_c-M} l_c
// ---------------------------------------------------------------------------
__launch_bounds__(256)
__global__ void attn_combine(const float* __restrict__ po, const float* __restrict__ pml,
                             float* __restrict__ out) {
  int idx = blockIdx.x * 256 + threadIdx.x;    // idx over B*T*DH = 1M
  int d   = idx & 63;
  int t   = (idx >> 6) & 4095;
  int b   = idx >> 18;
  int qt  = t >> 6;
  int rloc = t & 63;
  int ntiles = qt + 1;
  int cnt = (ntiles + NCHUNK - 1) / NCHUNK;

  float m_c[NCHUNK], l_c[NCHUNK], o_c[NCHUNK];
  float M = -1e30f;
#pragma unroll
  for (int c = 0; c < NCHUNK; ++c) {
    bool valid = (c * cnt < ntiles);
    int slot = ((b * 64 + qt) * NCHUNK + c);
    m_c[c] = valid ? pml[(size_t)slot * 128 + rloc]      : -1e30f;
    l_c[c] = valid ? pml[(size_t)slot * 128 + 64 + rloc] : 0.f;
    o_c[c] = valid ? po[(size_t)slot * (64 * 64) + rloc * 64 + d] : 0.f;
    M = fmaxf(M, m_c[c]);
  }
  float den = 0.f, num = 0.f;
#pragma unroll
  for (int c = 0; c < NCHUNK; ++c) {
    float e = __expf(m_c[c] - M);
    den += e * l_c[c];
    num += e * o_c[c];
  }
  out[idx] = num / den;
}

// ---------------------------------------------------------------------------
extern "C" void kernel_launch(void* const* d_in, const int* in_sizes, int n_in,
                              void* d_out, int out_size, void* d_ws, size_t ws_size,
                              hipStream_t stream) {
  const float* x  = (const float*)d_in[0];
  const float* Wq = (const float*)d_in[1];
  const float* Wk = (const float*)d_in[2];
  const float* Wv = (const float*)d_in[3];
  const float* fc = (const float*)d_in[4];
  const float* fs = (const float*)d_in[5];
  float* out = (float*)d_out;

  // workspace layout (~23 MB):
  char* ws = (char*)d_ws;
  u16*   wf    = (u16*)(ws);                                   // 384 KB (pad 512K)
  u16*   q_ws  = (u16*)(ws + (1u << 19));                      // 2 MB
  u16*   k_ws  = (u16*)(ws + (1u << 19) + (1u << 21));         // 2 MB
  u16*   vt_ws = (u16*)(ws + (1u << 19) + (2u << 21));         // 2 MB
  float* po    = (float*)(ws + (1u << 19) + (3u << 21));       // 1024*4096*4 = 16 MB
  float* pml   = (float*)(ws + (1u << 19) + (3u << 21) + (1u << 24)); // 512 KB

  prep_w<<<(3 * DH * CEMB + 255) / 256, 256, 0, stream>>>(Wq, Wk, Wv, wf);
  qkv_gemm<<<dim3(512), 256, 0, stream>>>(x, wf, fc, fs, q_ws, k_ws, vt_ws);
  attn_partial<<<dim3(256, NCHUNK), 256, 0, stream>>>(q_ws, k_ws, vt_ws, po, pml);
  attn_combine<<<dim3((NB * TSEQ * DH) / 256), 256, 0, stream>>>(po, pml, out);
}